// Round 1
// baseline (376.263 us; speedup 1.0000x reference)
//
#include <hip/hip_runtime.h>

#define DEVI __device__ __forceinline__

typedef _Float16 f16;
typedef _Float16 f16x8 __attribute__((ext_vector_type(8)));
typedef float f32x4 __attribute__((ext_vector_type(4)));
typedef unsigned int u32;
typedef unsigned long long u64;

#define MM 3
#define BBATCH 8192
#define DDIM 2000
#define ZDIM 256
#define KATT 40
#define K0P 2048
#define N0 1024
#define N1 512
#define N2 256

typedef __attribute__((address_space(1))) u32 gu32;
typedef __attribute__((address_space(3))) u32 lu32;

DEVI void async16(const void* g, void* l) {
  __builtin_amdgcn_global_load_lds((const gu32*)g, (lu32*)l, 16, 0, 0);
}

// ---------------- x -> fp16, K padded 2000 -> 2048 ----------------
__global__ void k_convx(const float* __restrict__ x, f16* __restrict__ xh) {
  const long long nch = (long long)MM * BBATCH * (K0P / 8);
  for (long long idx = (long long)blockIdx.x * blockDim.x + threadIdx.x; idx < nch;
       idx += (long long)gridDim.x * blockDim.x) {
    int c8 = (int)(idx & 255);
    long long row = idx >> 8;
    union { f16 h[8]; f16x8 v; } u;
    if (c8 < DDIM / 8) {
      const float* src = x + row * DDIM + c8 * 8;
      float4 a = *reinterpret_cast<const float4*>(src);
      float4 b = *reinterpret_cast<const float4*>(src + 4);
      u.h[0] = (f16)a.x; u.h[1] = (f16)a.y; u.h[2] = (f16)a.z; u.h[3] = (f16)a.w;
      u.h[4] = (f16)b.x; u.h[5] = (f16)b.y; u.h[6] = (f16)b.z; u.h[7] = (f16)b.w;
    } else {
      for (int j = 0; j < 8; ++j) u.h[j] = (f16)0.f;
    }
    *reinterpret_cast<f16x8*>(xh + row * K0P + c8 * 8) = u.v;
  }
}

// ---------------- weight transpose+convert: w[m][K][N] f32 -> wt[m][N][Kpad] f16 ----------------
__global__ void k_wt(const float* __restrict__ w, f16* __restrict__ wt, int K, int Kpad, int N) {
  __shared__ float tile[32][33];
  int m = blockIdx.z;
  int k0 = blockIdx.x * 32, n0 = blockIdx.y * 32;
  const float* wm = w + (long long)m * K * N;
  f16* wtm = wt + (long long)m * N * Kpad;
  for (int p = 0; p < 4; ++p) {
    int idx = threadIdx.x + p * 256;
    int kk = idx >> 5, nn = idx & 31;
    float v = 0.f;
    if (k0 + kk < K) v = wm[(long long)(k0 + kk) * N + n0 + nn];
    tile[kk][nn] = v;
  }
  __syncthreads();
  for (int p = 0; p < 4; ++p) {
    int idx = threadIdx.x + p * 256;
    int nn = idx >> 5, kk = idx & 31;
    wtm[(long long)(n0 + nn) * Kpad + k0 + kk] = (f16)tile[kk][nn];
  }
}

// ---------------- GEMM: C[m] = relu(A[m] @ BT[m]^T + bias), 128x128 tile, BK=64 ----------------
// A: [3][8192][K] f16 row-major; BT: [3][N][K] f16 (i.e. weight transposed); LDS XOR-swizzled.
template <int OUTF16>
__global__ __launch_bounds__(256, 2) void k_gemm(const f16* __restrict__ A,
                                                 const f16* __restrict__ BT,
                                                 const float* __restrict__ bias,
                                                 f16* __restrict__ outh,
                                                 float* __restrict__ outf, int K, int N) {
  __shared__ f16 As[128 * 64];
  __shared__ f16 Bs[128 * 64];
  const int m = blockIdx.z;
  const int gm0 = blockIdx.y * 128;
  const int gn0 = blockIdx.x * 128;
  const int tid = threadIdx.x;
  const int wave = tid >> 6, lane = tid & 63;
  const int wr = wave >> 1, wc = wave & 1;

  const f16* Am = A + (long long)m * BBATCH * K;
  const f16* Bm = BT + (long long)m * N * K;

  // staging: each wave stages 32 rows of A-tile and B-tile; 8 lanes per 128B row.
  // LDS dest is linear (lane*16); global source slot is pre-XOR-swizzled.
  const int srow = wave * 32 + (lane >> 3);
  const int sslot = (lane & 7) ^ (lane >> 3);  // phys slot (lane&7) holds logical slot s^ (row&7)
  const f16* aSrc = Am + (long long)(gm0 + srow) * K + sslot * 8;
  const f16* bSrc = Bm + (long long)(gn0 + srow) * K + sslot * 8;
  char* AsB = (char*)As;
  char* BsB = (char*)Bs;

  f32x4 zero = {0.f, 0.f, 0.f, 0.f};
  f32x4 acc[4][4];
  for (int i = 0; i < 4; ++i)
    for (int j = 0; j < 4; ++j) acc[i][j] = zero;

  for (int kt = 0; kt < K; kt += 64) {
    if (kt) __syncthreads();
#pragma unroll
    for (int q = 0; q < 4; ++q) {
      async16(aSrc + (long long)q * 8 * K + kt, AsB + (wave * 32 + q * 8) * 128);
      async16(bSrc + (long long)q * 8 * K + kt, BsB + (wave * 32 + q * 8) * 128);
    }
    __syncthreads();
#pragma unroll
    for (int ks = 0; ks < 2; ++ks) {
      f16x8 af[4], bf[4];
#pragma unroll
      for (int i = 0; i < 4; ++i) {
        int row = wr * 64 + i * 16 + (lane & 15);
        int slot = (ks * 4 + (lane >> 4)) ^ (row & 7);
        af[i] = *reinterpret_cast<const f16x8*>(AsB + row * 128 + slot * 16);
      }
#pragma unroll
      for (int j = 0; j < 4; ++j) {
        int row = wc * 64 + j * 16 + (lane & 15);
        int slot = (ks * 4 + (lane >> 4)) ^ (row & 7);
        bf[j] = *reinterpret_cast<const f16x8*>(BsB + row * 128 + slot * 16);
      }
#pragma unroll
      for (int i = 0; i < 4; ++i)
#pragma unroll
        for (int j = 0; j < 4; ++j)
          acc[i][j] = __builtin_amdgcn_mfma_f32_16x16x32_f16(af[i], bf[j], acc[i][j], 0, 0, 0);
    }
  }

  const int rowl = (lane >> 4) * 4;
  const int coll = lane & 15;
  for (int j = 0; j < 4; ++j) {
    int col = gn0 + wc * 64 + j * 16 + coll;
    float bv = bias[m * N + col];
    for (int i = 0; i < 4; ++i) {
      int row0 = gm0 + wr * 64 + i * 16 + rowl;
      for (int r = 0; r < 4; ++r) {
        float v = acc[i][j][r] + bv;
        v = v > 0.f ? v : 0.f;
        if constexpr (OUTF16) {
          outh[((long long)m * BBATCH + row0 + r) * N + col] = (f16)v;
        } else {
          outf[((long long)m * BBATCH + row0 + r) * N + col] = v;
        }
      }
    }
  }
}

// ---------------- fused attention tail ----------------
// Per block: 16 batch rows. Needs only aff[0], aff[1]; 3 matvecs:
//   p0: v = A0 @ t1 (for afm(0,1)), p1: v = A1 @ t2 (afm(0,2)), p2: v = A0 @ t2 (afm(1,2))
__global__ void k_attn(const float* __restrict__ z, const float* __restrict__ aff,
                       const float* __restrict__ W, const float* __restrict__ Wh,
                       float* __restrict__ out) {
  __shared__ f16 Ah[2 * 128 * 128];   // 64 KiB, rows 256B, XOR-swizzled slots
  __shared__ f16 tT[3 * 32 * 128];    // t transposed: [m][(bb,c)][f], swizzled
  __shared__ f16 vT[3 * 32 * 128];    // v transposed: [p][(bb,d)][f], swizzled
  __shared__ float Wt_l[3 * 16 * 82]; // [m][bb][k*2+c] (82 pad vs bank stride)
  __shared__ float afm_l[3 * 16 * 4];
  __shared__ float aa_l[16 * 6 * 2];
  __shared__ float Wh_l[9 * 40];

  const int tid = threadIdx.x;
  const int bbase = blockIdx.x * 16;

  // stage A0,A1 -> fp16 swizzled
  for (int i = tid; i < 2 * 128 * 128 / 2; i += 256) {
    int k = i >> 13;
    int r = (i >> 6) & 127;
    int g2 = i & 63;
    float2 v = *reinterpret_cast<const float2*>(aff + (((long long)k * 128 + r) * 128 + g2 * 2));
    union { f16 h[2]; u32 u; } pk;
    pk.h[0] = (f16)v.x; pk.h[1] = (f16)v.y;
    int bo = (k * 128 + r) * 256 + ((g2 * 4) ^ ((r & 7) << 4));
    *reinterpret_cast<u32*>((char*)Ah + bo) = pk.u;
  }
  // stage t transposed: tT[m][bb*2+c][f] = z[m][bbase+bb][2f+c]
  for (int i = tid; i < 3 * 16 * 256; i += 256) {
    int mI = i >> 12;
    int rem = i & 4095;
    int bb = rem >> 8;
    int zz = rem & 255;
    float v = z[((long long)mI * BBATCH + bbase + bb) * ZDIM + zz];
    int row = bb * 2 + (zz & 1);
    int f = zz >> 1;
    int bo = (mI * 32 + row) * 256 + ((f * 2) ^ ((row & 7) << 4));
    *reinterpret_cast<f16*>((char*)tT + bo) = (f16)v;
  }
  for (int i = tid; i < 360; i += 256) Wh_l[i] = Wh[i];
  __syncthreads();

  // P1: the 3 matvecs as 128x32x128 MFMA; wave w owns f-rows [w*32, w*32+32)
  {
    const int lane = tid & 63, wv = tid >> 6;
    f32x4 zero = {0.f, 0.f, 0.f, 0.f};
#pragma unroll
    for (int p = 0; p < 3; ++p) {
      const int jm = (p == 0) ? 1 : 2;
      const int km = (p == 1) ? 1 : 0;
      const char* Abase = (const char*)Ah + km * 32768;
      const char* Tbase = (const char*)tT + jm * 8192;
      f32x4 acc[2][2] = {{zero, zero}, {zero, zero}};
#pragma unroll
      for (int ks = 0; ks < 4; ++ks) {
        f16x8 afr[2], bfr[2];
#pragma unroll
        for (int mf = 0; mf < 2; ++mf) {
          int row = wv * 32 + mf * 16 + (lane & 15);
          int slot = (ks * 4 + (lane >> 4)) ^ (row & 7);
          afr[mf] = *reinterpret_cast<const f16x8*>(Abase + row * 256 + slot * 16);
        }
#pragma unroll
        for (int nf = 0; nf < 2; ++nf) {
          int row = nf * 16 + (lane & 15);
          int slot = (ks * 4 + (lane >> 4)) ^ (row & 7);
          bfr[nf] = *reinterpret_cast<const f16x8*>(Tbase + row * 256 + slot * 16);
        }
#pragma unroll
        for (int mf = 0; mf < 2; ++mf)
#pragma unroll
          for (int nf = 0; nf < 2; ++nf)
            acc[mf][nf] = __builtin_amdgcn_mfma_f32_16x16x32_f16(afr[mf], bfr[nf], acc[mf][nf], 0, 0, 0);
      }
#pragma unroll
      for (int mf = 0; mf < 2; ++mf)
#pragma unroll
        for (int nf = 0; nf < 2; ++nf) {
          int col = nf * 16 + (lane & 15);
          int f0 = wv * 32 + mf * 16 + (lane >> 4) * 4;
          union { f16 h[4]; u64 q; } pk;
          pk.h[0] = (f16)acc[mf][nf][0];
          pk.h[1] = (f16)acc[mf][nf][1];
          pk.h[2] = (f16)acc[mf][nf][2];
          pk.h[3] = (f16)acc[mf][nf][3];
          int bo = (p * 32 + col) * 256 + ((f0 * 2) ^ ((col & 7) << 4));
          *reinterpret_cast<u64*>((char*)vT + bo) = pk.q;
        }
    }
  }
  __syncthreads();

  // P2: afm[p][bb][c][d] = sum_f t_i[f][c] * v_p[f][d]   (i = p>>1 gives {0,0,1})
  if (tid < 192) {
    int p = tid >> 6;
    int r = tid & 63;
    int bb = r >> 2, c = (r >> 1) & 1, d = r & 1;
    int iM = p >> 1;
    const char* tb = (const char*)tT + iM * 8192;
    const char* vb = (const char*)vT + p * 8192;
    int rowt = bb * 2 + c, rowv = bb * 2 + d;
    int mt = (rowt & 7) << 4, mv = (rowv & 7) << 4;
    float s = 0.f;
    for (int ch = 0; ch < 16; ++ch) {
      f16x8 tv = *reinterpret_cast<const f16x8*>(tb + rowt * 256 + ((ch * 16) ^ mt));
      f16x8 vv = *reinterpret_cast<const f16x8*>(vb + rowv * 256 + ((ch * 16) ^ mv));
      for (int q = 0; q < 8; ++q) s += (float)tv[q] * (float)vv[q];
    }
    afm_l[(p * 16 + bb) * 4 + c * 2 + d] = s;
  }
  // P3: Wt[m][bb][k][c] = sum_f W[m][k][f] * t_m[f][c]
  for (int it = 0; it < 8; ++it) {
    int item = tid + it * 256;
    if (item < 1920) {
      int bb = item & 15;
      int mk = item >> 4;
      int mI = mk / 40, k = mk % 40;
      const float* wrow = W + (mI * 40 + k) * 128;
      const char* t0 = (const char*)tT + mI * 8192 + (bb * 2 + 0) * 256;
      const char* t1 = (const char*)tT + mI * 8192 + (bb * 2 + 1) * 256;
      int m0 = ((bb * 2) & 7) << 4, m1 = ((bb * 2 + 1) & 7) << 4;
      float s0 = 0.f, s1 = 0.f;
      for (int ch = 0; ch < 16; ++ch) {
        float4 w0 = *reinterpret_cast<const float4*>(wrow + ch * 8);
        float4 w1 = *reinterpret_cast<const float4*>(wrow + ch * 8 + 4);
        f16x8 ta = *reinterpret_cast<const f16x8*>(t0 + ((ch * 16) ^ m0));
        f16x8 tb2 = *reinterpret_cast<const f16x8*>(t1 + ((ch * 16) ^ m1));
        s0 += w0.x * (float)ta[0] + w0.y * (float)ta[1] + w0.z * (float)ta[2] + w0.w * (float)ta[3] +
              w1.x * (float)ta[4] + w1.y * (float)ta[5] + w1.z * (float)ta[6] + w1.w * (float)ta[7];
        s1 += w0.x * (float)tb2[0] + w0.y * (float)tb2[1] + w0.z * (float)tb2[2] + w0.w * (float)tb2[3] +
              w1.x * (float)tb2[4] + w1.y * (float)tb2[5] + w1.z * (float)tb2[6] + w1.w * (float)tb2[7];
      }
      Wt_l[(mI * 16 + bb) * 82 + k * 2 + 0] = s0;
      Wt_l[(mI * 16 + bb) * 82 + k * 2 + 1] = s1;
    }
  }
  __syncthreads();

  // P4a: H, s, softmax -> aa
  if (tid < 96) {
    int bb = tid / 6, q = tid % 6;
    int i = q >> 1;
    int j = (q & 1) ? ((i == 2) ? 1 : 2) : ((i == 0) ? 1 : 0);
    int a = i < j ? i : j;
    int b2 = i < j ? j : i;
    int pidx = a + b2 - 1;
    bool trans = (i > j);
    const float* af = &afm_l[(pidx * 16 + bb) * 4];
    float m00, m01, m10, m11;  // Aeff[d][c]
    if (!trans) { m00 = af[0]; m01 = af[1]; m10 = af[2]; m11 = af[3]; }
    else        { m00 = af[0]; m01 = af[2]; m10 = af[1]; m11 = af[3]; }
    const float* wb = &Wt_l[(b2 * 16 + bb) * 82];
    const float* wa = &Wt_l[(a * 16 + bb) * 82];
    const float* wh = &Wh_l[(i * 3 + j) * 40];
    float s0 = 0.f, s1 = 0.f;
    for (int k = 0; k < 40; ++k) {
      float b0v = wb[k * 2], b1v = wb[k * 2 + 1];
      float a0v = wa[k * 2], a1v = wa[k * 2 + 1];
      float h0 = tanhf(b0v + a0v * m00 + a1v * m10);
      float h1 = tanhf(b1v + a0v * m01 + a1v * m11);
      float w = wh[k];
      s0 += w * h0;
      s1 += w * h1;
    }
    float mx = fmaxf(s0, s1);
    float e0 = __expf(s0 - mx), e1 = __expf(s1 - mx);
    float inv = 1.f / (e0 + e1);
    aa_l[(bb * 6 + q) * 2 + 0] = e0 * inv;
    aa_l[(bb * 6 + q) * 2 + 1] = e1 * inv;
  }
  __syncthreads();

  // P4b: out[b][q*256+zz] = a[b][q][zz&1] * z[i(q)][b][zz]  (coalesced)
  for (int i2 = tid; i2 < 16 * 6 * 256; i2 += 256) {
    int zz = i2 & 255;
    int r = i2 >> 8;
    int q = r % 6;
    int bb = r / 6;
    int iM = q >> 1;
    float a = aa_l[(bb * 6 + q) * 2 + (zz & 1)];
    float tv = z[((long long)iM * BBATCH + bbase + bb) * ZDIM + zz];
    out[(long long)(bbase + bb) * 1536 + q * 256 + zz] = a * tv;
  }
}

extern "C" void kernel_launch(void* const* d_in, const int* in_sizes, int n_in, void* d_out,
                              int out_size, void* d_ws, size_t ws_size, hipStream_t stream) {
  const float* x = (const float*)d_in[0];
  const float* w0 = (const float*)d_in[1];
  const float* b0 = (const float*)d_in[2];
  const float* w1 = (const float*)d_in[3];
  const float* b1 = (const float*)d_in[4];
  const float* w2 = (const float*)d_in[5];
  const float* b2 = (const float*)d_in[6];
  const float* aff = (const float*)d_in[7];
  const float* W = (const float*)d_in[8];
  const float* Wh = (const float*)d_in[9];
  float* zout = (float*)d_out;
  float* cout = zout + (long long)MM * BBATCH * ZDIM;

  char* ws = (char*)d_ws;
  size_t off = 0;
  auto alloc = [&](size_t bytes) {
    char* p = ws + off;
    off += (bytes + 255) & ~(size_t)255;
    return p;
  };
  f16* xh = (f16*)alloc((size_t)MM * BBATCH * K0P * 2);
  f16* wT0 = (f16*)alloc((size_t)MM * N0 * K0P * 2);
  f16* wT1 = (f16*)alloc((size_t)MM * N1 * N0 * 2);
  f16* wT2 = (f16*)alloc((size_t)MM * N2 * N1 * 2);
  f16* h0 = (f16*)alloc((size_t)MM * BBATCH * N0 * 2);
  f16* h1 = (f16*)alloc((size_t)MM * BBATCH * N1 * 2);
  if (ws_size < off) return;  // workspace too small: bail deterministically

  k_convx<<<4096, 256, 0, stream>>>(x, xh);
  k_wt<<<dim3(K0P / 32, N0 / 32, 3), 256, 0, stream>>>(w0, wT0, DDIM, K0P, N0);
  k_wt<<<dim3(N0 / 32, N1 / 32, 3), 256, 0, stream>>>(w1, wT1, N0, N0, N1);
  k_wt<<<dim3(N1 / 32, N2 / 32, 3), 256, 0, stream>>>(w2, wT2, N1, N1, N2);
  k_gemm<1><<<dim3(N0 / 128, BBATCH / 128, 3), 256, 0, stream>>>(xh, wT0, b0, h0, nullptr, K0P, N0);
  k_gemm<1><<<dim3(N1 / 128, BBATCH / 128, 3), 256, 0, stream>>>(h0, wT1, b1, h1, nullptr, N0, N1);
  k_gemm<0><<<dim3(N2 / 128, BBATCH / 128, 3), 256, 0, stream>>>(h1, wT2, b2, nullptr, zout, N1, N2);
  k_attn<<<BBATCH / 16, 256, 0, stream>>>(zout, aff, W, Wh, cout);
}

// Round 2
// 314.318 us; speedup vs baseline: 1.1971x; 1.1971x over previous
//
#include <hip/hip_runtime.h>

#define DEVI __device__ __forceinline__

typedef _Float16 f16;
typedef _Float16 f16x8 __attribute__((ext_vector_type(8)));
typedef float f32x4 __attribute__((ext_vector_type(4)));
typedef unsigned int u32;
typedef unsigned long long u64;

#define MM 3
#define BBATCH 8192
#define DDIM 2000
#define ZDIM 256
#define KATT 40
#define K0P 2048
#define N0 1024
#define N1 512
#define N2 256

typedef __attribute__((address_space(1))) u32 gu32;
typedef __attribute__((address_space(3))) u32 lu32;

DEVI void async16(const void* g, void* l) {
  __builtin_amdgcn_global_load_lds((const gu32*)g, (lu32*)l, 16, 0, 0);
}

// ---------------- x -> fp16, K padded 2000 -> 2048 ----------------
__global__ void k_convx(const float* __restrict__ x, f16* __restrict__ xh) {
  const long long nch = (long long)MM * BBATCH * (K0P / 8);
  for (long long idx = (long long)blockIdx.x * blockDim.x + threadIdx.x; idx < nch;
       idx += (long long)gridDim.x * blockDim.x) {
    int c8 = (int)(idx & 255);
    long long row = idx >> 8;
    union { f16 h[8]; f16x8 v; } u;
    if (c8 < DDIM / 8) {
      const float* src = x + row * DDIM + c8 * 8;
      float4 a = *reinterpret_cast<const float4*>(src);
      float4 b = *reinterpret_cast<const float4*>(src + 4);
      u.h[0] = (f16)a.x; u.h[1] = (f16)a.y; u.h[2] = (f16)a.z; u.h[3] = (f16)a.w;
      u.h[4] = (f16)b.x; u.h[5] = (f16)b.y; u.h[6] = (f16)b.z; u.h[7] = (f16)b.w;
    } else {
      for (int j = 0; j < 8; ++j) u.h[j] = (f16)0.f;
    }
    *reinterpret_cast<f16x8*>(xh + row * K0P + c8 * 8) = u.v;
  }
}

// ---------------- weight transpose+convert: w[m][K][N] f32 -> wt[m][N][Kpad] f16 ----------------
__global__ void k_wt(const float* __restrict__ w, f16* __restrict__ wt, int K, int Kpad, int N) {
  __shared__ float tile[32][33];
  int m = blockIdx.z;
  int k0 = blockIdx.x * 32, n0 = blockIdx.y * 32;
  const float* wm = w + (long long)m * K * N;
  f16* wtm = wt + (long long)m * N * Kpad;
  for (int p = 0; p < 4; ++p) {
    int idx = threadIdx.x + p * 256;
    int kk = idx >> 5, nn = idx & 31;
    float v = 0.f;
    if (k0 + kk < K) v = wm[(long long)(k0 + kk) * N + n0 + nn];
    tile[kk][nn] = v;
  }
  __syncthreads();
  for (int p = 0; p < 4; ++p) {
    int idx = threadIdx.x + p * 256;
    int nn = idx >> 5, kk = idx & 31;
    wtm[(long long)(n0 + nn) * Kpad + k0 + kk] = (f16)tile[kk][nn];
  }
}

// ---------------- small converts: aff -> f16, W -> f16 zero-padded [3][64][128] ----------------
__global__ void k_convsmall(const float* __restrict__ aff, const float* __restrict__ W,
                            f16* __restrict__ affH, f16* __restrict__ WH) {
  int idx = blockIdx.x * 256 + threadIdx.x;
  if (idx < 2 * 128 * 128) affH[idx] = (f16)aff[idx];
  if (idx < 3 * 64 * 128) {
    int m = idx >> 13;
    int k = (idx >> 7) & 63;
    int f = idx & 127;
    WH[idx] = (k < KATT) ? (f16)W[(m * KATT + k) * 128 + f] : (f16)0.f;
  }
}

// ---------------- GEMM: C[m] = relu(A[m] @ BT[m]^T + bias), 128x128 tile, BK=64 ----------------
// OUTF16=1: write f16 hidden. OUTF16=0: write f32 z AND de-interleaved f16 tH[m][(b*2+c)][g].
template <int OUTF16>
__global__ __launch_bounds__(256, 2) void k_gemm(const f16* __restrict__ A,
                                                 const f16* __restrict__ BT,
                                                 const float* __restrict__ bias,
                                                 f16* __restrict__ outh,
                                                 float* __restrict__ outf,
                                                 f16* __restrict__ tH, int K, int N) {
  __shared__ f16 As[128 * 64];
  __shared__ f16 Bs[128 * 64];
  const int m = blockIdx.z;
  const int gm0 = blockIdx.y * 128;
  const int gn0 = blockIdx.x * 128;
  const int tid = threadIdx.x;
  const int wave = tid >> 6, lane = tid & 63;
  const int wr = wave >> 1, wc = wave & 1;

  const f16* Am = A + (long long)m * BBATCH * K;
  const f16* Bm = BT + (long long)m * N * K;

  const int srow = wave * 32 + (lane >> 3);
  const int sslot = (lane & 7) ^ (lane >> 3);
  const f16* aSrc = Am + (long long)(gm0 + srow) * K + sslot * 8;
  const f16* bSrc = Bm + (long long)(gn0 + srow) * K + sslot * 8;
  char* AsB = (char*)As;
  char* BsB = (char*)Bs;

  f32x4 zero = {0.f, 0.f, 0.f, 0.f};
  f32x4 acc[4][4];
  for (int i = 0; i < 4; ++i)
    for (int j = 0; j < 4; ++j) acc[i][j] = zero;

  for (int kt = 0; kt < K; kt += 64) {
    if (kt) __syncthreads();
#pragma unroll
    for (int q = 0; q < 4; ++q) {
      async16(aSrc + (long long)q * 8 * K + kt, AsB + (wave * 32 + q * 8) * 128);
      async16(bSrc + (long long)q * 8 * K + kt, BsB + (wave * 32 + q * 8) * 128);
    }
    __syncthreads();
#pragma unroll
    for (int ks = 0; ks < 2; ++ks) {
      f16x8 af[4], bf[4];
#pragma unroll
      for (int i = 0; i < 4; ++i) {
        int row = wr * 64 + i * 16 + (lane & 15);
        int slot = (ks * 4 + (lane >> 4)) ^ (row & 7);
        af[i] = *reinterpret_cast<const f16x8*>(AsB + row * 128 + slot * 16);
      }
#pragma unroll
      for (int j = 0; j < 4; ++j) {
        int row = wc * 64 + j * 16 + (lane & 15);
        int slot = (ks * 4 + (lane >> 4)) ^ (row & 7);
        bf[j] = *reinterpret_cast<const f16x8*>(BsB + row * 128 + slot * 16);
      }
#pragma unroll
      for (int i = 0; i < 4; ++i)
#pragma unroll
        for (int j = 0; j < 4; ++j)
          acc[i][j] = __builtin_amdgcn_mfma_f32_16x16x32_f16(af[i], bf[j], acc[i][j], 0, 0, 0);
    }
  }

  const int rowl = (lane >> 4) * 4;
  const int coll = lane & 15;
  for (int j = 0; j < 4; ++j) {
    int col = gn0 + wc * 64 + j * 16 + coll;
    float bv = bias[m * N + col];
    for (int i = 0; i < 4; ++i) {
      int row0 = gm0 + wr * 64 + i * 16 + rowl;
      for (int r = 0; r < 4; ++r) {
        float v = acc[i][j][r] + bv;
        v = v > 0.f ? v : 0.f;
        if constexpr (OUTF16) {
          outh[((long long)m * BBATCH + row0 + r) * N + col] = (f16)v;
        } else {
          outf[((long long)m * BBATCH + row0 + r) * N + col] = v;
          tH[((long long)(m * BBATCH + row0 + r) * 2 + (col & 1)) * 128 + (col >> 1)] = (f16)v;
        }
      }
    }
  }
}

// ---------------- small GEMMs for the attention tail ----------------
// z-block 0..2 (p): u[p][(b*2+d)][f] = sum_g affH[km(p)][f][g] * tH[jm(p)][(b*2+d)][g]   (f16 out)
// z-block 3..5 (m): WtG[m][(b*2+c)][k] = sum_f WH[m][k][f] * tH[m][(b*2+c)][f]          (f32 out)
__global__ __launch_bounds__(256, 2) void k_sg(const f16* __restrict__ tH,
                                               const f16* __restrict__ affH,
                                               const f16* __restrict__ WH,
                                               f16* __restrict__ u, float* __restrict__ WtG) {
  __shared__ f16 As[128 * 128];
  __shared__ f16 Bs[128 * 128];
  const int zb = blockIdx.z;
  const int gm0 = blockIdx.y * 128;
  const bool isU = (zb < 3);
  const int p = isU ? zb : zb - 3;
  const int src = isU ? ((p == 0) ? 1 : 2) : p;
  const f16* Am = tH + (long long)src * 16384 * 128;
  const f16* Bm;
  int brows;
  if (isU) {
    int km = (p == 1) ? 1 : 0;
    Bm = affH + km * 128 * 128;
    brows = 128;
  } else {
    Bm = WH + p * 64 * 128;
    brows = 64;
  }

  const int tid = threadIdx.x;
  const int wave = tid >> 6, lane = tid & 63;
  const int wr = wave >> 1, wc = wave & 1;
  char* AsB = (char*)As;
  char* BsB = (char*)Bs;

#pragma unroll
  for (int q = 0; q < 8; ++q) {
    int sb = q * 4 + wave;
    int row = sb * 4 + (lane >> 4);
    int lsl = (lane & 15) ^ (row & 7);
    async16(Am + (long long)(gm0 + row) * 128 + lsl * 8, AsB + sb * 1024);
    if (sb * 4 < brows)
      async16(Bm + (long long)row * 128 + lsl * 8, BsB + sb * 1024);
  }
  if (brows == 64) {
    f16x8 z8 = {};
    for (int idx = tid; idx < 1024; idx += 256) {
      int row = 64 + (idx >> 4), sl = idx & 15;
      *reinterpret_cast<f16x8*>(BsB + row * 256 + sl * 16) = z8;
    }
  }
  __syncthreads();

  f32x4 zero = {0.f, 0.f, 0.f, 0.f};
  f32x4 acc[4][4];
  for (int i = 0; i < 4; ++i)
    for (int j = 0; j < 4; ++j) acc[i][j] = zero;

#pragma unroll
  for (int ks = 0; ks < 4; ++ks) {
    f16x8 af[4], bf[4];
#pragma unroll
    for (int i = 0; i < 4; ++i) {
      int row = wr * 64 + i * 16 + (lane & 15);
      int slot = (ks * 4 + (lane >> 4)) ^ (row & 7);
      af[i] = *reinterpret_cast<const f16x8*>(AsB + row * 256 + slot * 16);
    }
#pragma unroll
    for (int j = 0; j < 4; ++j) {
      int row = wc * 64 + j * 16 + (lane & 15);
      int slot = (ks * 4 + (lane >> 4)) ^ (row & 7);
      bf[j] = *reinterpret_cast<const f16x8*>(BsB + row * 256 + slot * 16);
    }
#pragma unroll
    for (int i = 0; i < 4; ++i)
#pragma unroll
      for (int j = 0; j < 4; ++j)
        acc[i][j] = __builtin_amdgcn_mfma_f32_16x16x32_f16(af[i], bf[j], acc[i][j], 0, 0, 0);
  }

  const int rowl = (lane >> 4) * 4;
  const int coll = lane & 15;
  if (isU) {
    for (int j = 0; j < 4; ++j) {
      int col = wc * 64 + j * 16 + coll;
      for (int i = 0; i < 4; ++i) {
        int row0 = gm0 + wr * 64 + i * 16 + rowl;
        for (int r = 0; r < 4; ++r)
          u[((long long)p * 16384 + row0 + r) * 128 + col] = (f16)acc[i][j][r];
      }
    }
  } else if (wc == 0) {
    for (int j = 0; j < 4; ++j) {
      int col = j * 16 + coll;
      for (int i = 0; i < 4; ++i) {
        int row0 = gm0 + wr * 64 + i * 16 + rowl;
        for (int r = 0; r < 4; ++r)
          WtG[((long long)p * 16384 + row0 + r) * 64 + col] = acc[i][j][r];
      }
    }
  }
}

// ---------------- fused tail: afm dots + tanh/softmax + coalesced output ----------------
DEVI float dot128(const f16* __restrict__ a, const f16* __restrict__ b) {
  float s = 0.f;
#pragma unroll
  for (int ch = 0; ch < 16; ++ch) {
    f16x8 av = *reinterpret_cast<const f16x8*>(a + ch * 8);
    f16x8 bv = *reinterpret_cast<const f16x8*>(b + ch * 8);
#pragma unroll
    for (int q = 0; q < 8; ++q) s += (float)av[q] * (float)bv[q];
  }
  return s;
}

DEVI float ftanh(float x) {
  x = fminf(fmaxf(x, -15.f), 15.f);
  float t = __expf(-2.f * x);
  return (1.f - t) / (1.f + t);
}

#define BB 32
__global__ void k_tail(const float* __restrict__ z, const f16* __restrict__ tH,
                       const f16* __restrict__ u, const float* __restrict__ WtG,
                       const float* __restrict__ Wh, float* __restrict__ out) {
  __shared__ float aa[BB][6][2];
  const int tid = threadIdx.x;
  const int bbase = blockIdx.x * BB;

  if (tid < BB * 6) {
    int bb = tid / 6, q = tid % 6;
    int b = bbase + bb;
    int i = q >> 1;
    int j = (q & 1) ? ((i == 2) ? 1 : 2) : ((i == 0) ? 1 : 0);
    int a = i < j ? i : j;
    int b2 = i < j ? j : i;
    int pidx = a + b2 - 1;
    bool trans = (i > j);

    // afm[c][d] = sum_f tH[a][(b*2+c)][f] * u[pidx][(b*2+d)][f]
    float afm[2][2];
#pragma unroll
    for (int c = 0; c < 2; ++c)
#pragma unroll
      for (int d = 0; d < 2; ++d)
        afm[c][d] = dot128(tH + ((long long)(a * BBATCH + b) * 2 + c) * 128,
                           u + ((long long)pidx * 16384 + b * 2 + d) * 128);

    float m00, m01, m10, m11;  // coefficient of (Wt_a[c], output d)
    if (!trans) { m00 = afm[0][0]; m01 = afm[0][1]; m10 = afm[1][0]; m11 = afm[1][1]; }
    else        { m00 = afm[0][0]; m01 = afm[1][0]; m10 = afm[0][1]; m11 = afm[1][1]; }

    const float* wb0 = WtG + ((long long)b2 * 16384 + b * 2 + 0) * 64;
    const float* wb1 = WtG + ((long long)b2 * 16384 + b * 2 + 1) * 64;
    const float* wa0 = WtG + ((long long)a * 16384 + b * 2 + 0) * 64;
    const float* wa1 = WtG + ((long long)a * 16384 + b * 2 + 1) * 64;
    const float* wh = Wh + (i * 3 + j) * KATT;
    float s0 = 0.f, s1 = 0.f;
    for (int k = 0; k < KATT; ++k) {
      float a0v = wa0[k], a1v = wa1[k];
      float h0 = ftanh(wb0[k] + a0v * m00 + a1v * m10);
      float h1 = ftanh(wb1[k] + a0v * m01 + a1v * m11);
      float w = wh[k];
      s0 += w * h0;
      s1 += w * h1;
    }
    float mx = fmaxf(s0, s1);
    float e0 = __expf(s0 - mx), e1 = __expf(s1 - mx);
    float inv = 1.f / (e0 + e1);
    aa[bb][q][0] = e0 * inv;
    aa[bb][q][1] = e1 * inv;
  }
  __syncthreads();

  for (int idx = tid; idx < BB * 6 * 256; idx += 256) {
    int zz = idx & 255;
    int r = idx >> 8;
    int q = r % 6;
    int bb = r / 6;
    int iM = q >> 1;
    float av = aa[bb][q][zz & 1];
    float tv = z[((long long)iM * BBATCH + bbase + bb) * ZDIM + zz];
    out[(long long)(bbase + bb) * 1536 + q * 256 + zz] = av * tv;
  }
}

extern "C" void kernel_launch(void* const* d_in, const int* in_sizes, int n_in, void* d_out,
                              int out_size, void* d_ws, size_t ws_size, hipStream_t stream) {
  const float* x = (const float*)d_in[0];
  const float* w0 = (const float*)d_in[1];
  const float* b0 = (const float*)d_in[2];
  const float* w1 = (const float*)d_in[3];
  const float* b1 = (const float*)d_in[4];
  const float* w2 = (const float*)d_in[5];
  const float* b2 = (const float*)d_in[6];
  const float* aff = (const float*)d_in[7];
  const float* W = (const float*)d_in[8];
  const float* Wh = (const float*)d_in[9];
  float* zout = (float*)d_out;
  float* cout = zout + (long long)MM * BBATCH * ZDIM;

  char* ws = (char*)d_ws;
  size_t off = 0;
  auto alloc = [&](size_t bytes) {
    char* p = ws + off;
    off += (bytes + 255) & ~(size_t)255;
    return p;
  };
  f16* xh = (f16*)alloc((size_t)MM * BBATCH * K0P * 2);
  f16* wT0 = (f16*)alloc((size_t)MM * N0 * K0P * 2);
  f16* wT1 = (f16*)alloc((size_t)MM * N1 * N0 * 2);
  f16* wT2 = (f16*)alloc((size_t)MM * N2 * N1 * 2);
  f16* h0 = (f16*)alloc((size_t)MM * BBATCH * N0 * 2);
  f16* h1 = (f16*)alloc((size_t)MM * BBATCH * N1 * 2);
  f16* affH = (f16*)alloc((size_t)2 * 128 * 128 * 2);
  f16* WH = (f16*)alloc((size_t)3 * 64 * 128 * 2);
  if (ws_size < off) return;

  // tH / u / WtG alias the xh region: xh is dead once the L0 GEMM completes, and
  // tH is only written by the L2 GEMM (after L0/L1), u/WtG by k_sg (after that).
  f16* tH = (f16*)xh;                                        // 3*16384*128 f16 = 12.6 MB
  f16* u = (f16*)((char*)xh + (size_t)3 * 16384 * 128 * 2);  // 12.6 MB
  float* WtG = (float*)((char*)xh + (size_t)2 * 3 * 16384 * 128 * 2);  // 3*16384*64 f32 = 12.6 MB

  k_convx<<<4096, 256, 0, stream>>>(x, xh);
  k_convsmall<<<128, 256, 0, stream>>>(aff, W, affH, WH);
  k_wt<<<dim3(K0P / 32, N0 / 32, 3), 256, 0, stream>>>(w0, wT0, DDIM, K0P, N0);
  k_wt<<<dim3(N0 / 32, N1 / 32, 3), 256, 0, stream>>>(w1, wT1, N0, N0, N1);
  k_wt<<<dim3(N1 / 32, N2 / 32, 3), 256, 0, stream>>>(w2, wT2, N1, N1, N2);
  k_gemm<1><<<dim3(N0 / 128, BBATCH / 128, 3), 256, 0, stream>>>(xh, wT0, b0, h0, nullptr, nullptr, K0P, N0);
  k_gemm<1><<<dim3(N1 / 128, BBATCH / 128, 3), 256, 0, stream>>>(h0, wT1, b1, h1, nullptr, nullptr, N0, N1);
  k_gemm<0><<<dim3(N2 / 128, BBATCH / 128, 3), 256, 0, stream>>>(h1, wT2, b2, nullptr, zout, tH, N1, N2);
  k_sg<<<dim3(1, 128, 6), 256, 0, stream>>>(tH, affH, WH, u, WtG);
  k_tail<<<256, 256, 0, stream>>>(zout, tH, u, WtG, Wh, cout);
}

// Round 3
// 305.556 us; speedup vs baseline: 1.2314x; 1.0287x over previous
//
#include <hip/hip_runtime.h>

#define DEVI __device__ __forceinline__

typedef _Float16 f16;
typedef _Float16 f16x8 __attribute__((ext_vector_type(8)));
typedef float f32x4 __attribute__((ext_vector_type(4)));
typedef unsigned int u32;
typedef unsigned long long u64;

#define MM 3
#define BBATCH 8192
#define DDIM 2000
#define ZDIM 256
#define KATT 40
#define K0P 2048
#define N0 1024
#define N1 512
#define N2 256

typedef __attribute__((address_space(1))) u32 gu32;
typedef __attribute__((address_space(3))) u32 lu32;

DEVI void async16(const void* g, void* l) {
  __builtin_amdgcn_global_load_lds((const gu32*)g, (lu32*)l, 16, 0, 0);
}

// ---------------- x -> fp16, K padded 2000 -> 2048 ----------------
__global__ void k_convx(const float* __restrict__ x, f16* __restrict__ xh) {
  const long long nch = (long long)MM * BBATCH * (K0P / 8);
  for (long long idx = (long long)blockIdx.x * blockDim.x + threadIdx.x; idx < nch;
       idx += (long long)gridDim.x * blockDim.x) {
    int c8 = (int)(idx & 255);
    long long row = idx >> 8;
    union { f16 h[8]; f16x8 v; } u;
    if (c8 < DDIM / 8) {
      const float* src = x + row * DDIM + c8 * 8;
      float4 a = *reinterpret_cast<const float4*>(src);
      float4 b = *reinterpret_cast<const float4*>(src + 4);
      u.h[0] = (f16)a.x; u.h[1] = (f16)a.y; u.h[2] = (f16)a.z; u.h[3] = (f16)a.w;
      u.h[4] = (f16)b.x; u.h[5] = (f16)b.y; u.h[6] = (f16)b.z; u.h[7] = (f16)b.w;
    } else {
      for (int j = 0; j < 8; ++j) u.h[j] = (f16)0.f;
    }
    *reinterpret_cast<f16x8*>(xh + row * K0P + c8 * 8) = u.v;
  }
}

// ---------------- weight transpose+convert: w[m][K][N] f32 -> wt[m][N][Kpad] f16 ----------------
__global__ void k_wt(const float* __restrict__ w, f16* __restrict__ wt, int K, int Kpad, int N) {
  __shared__ float tile[32][33];
  int m = blockIdx.z;
  int k0 = blockIdx.x * 32, n0 = blockIdx.y * 32;
  const float* wm = w + (long long)m * K * N;
  f16* wtm = wt + (long long)m * N * Kpad;
  for (int p = 0; p < 4; ++p) {
    int idx = threadIdx.x + p * 256;
    int kk = idx >> 5, nn = idx & 31;
    float v = 0.f;
    if (k0 + kk < K) v = wm[(long long)(k0 + kk) * N + n0 + nn];
    tile[kk][nn] = v;
  }
  __syncthreads();
  for (int p = 0; p < 4; ++p) {
    int idx = threadIdx.x + p * 256;
    int nn = idx >> 5, kk = idx & 31;
    wtm[(long long)(n0 + nn) * Kpad + k0 + kk] = (f16)tile[kk][nn];
  }
}

// ---------------- small converts: aff -> f16, W -> f16 zero-padded [3][64][128] ----------------
__global__ void k_convsmall(const float* __restrict__ aff, const float* __restrict__ W,
                            f16* __restrict__ affH, f16* __restrict__ WH) {
  int idx = blockIdx.x * 256 + threadIdx.x;
  if (idx < 2 * 128 * 128) affH[idx] = (f16)aff[idx];
  if (idx < 3 * 64 * 128) {
    int m = idx >> 13;
    int k = (idx >> 7) & 63;
    int f = idx & 127;
    WH[idx] = (k < KATT) ? (f16)W[(m * KATT + k) * 128 + f] : (f16)0.f;
  }
}

// ---------------- legacy GEMM (fallback path), 128x128 tile, BK=64 ----------------
template <int OUTF16>
__global__ __launch_bounds__(256, 2) void k_gemm(const f16* __restrict__ A,
                                                 const f16* __restrict__ BT,
                                                 const float* __restrict__ bias,
                                                 f16* __restrict__ outh,
                                                 float* __restrict__ outf,
                                                 f16* __restrict__ tH, int K, int N) {
  __shared__ f16 As[128 * 64];
  __shared__ f16 Bs[128 * 64];
  const int m = blockIdx.z;
  const int gm0 = blockIdx.y * 128;
  const int gn0 = blockIdx.x * 128;
  const int tid = threadIdx.x;
  const int wave = tid >> 6, lane = tid & 63;
  const int wr = wave >> 1, wc = wave & 1;

  const f16* Am = A + (long long)m * BBATCH * K;
  const f16* Bm = BT + (long long)m * N * K;

  const int srow = wave * 32 + (lane >> 3);
  const int sslot = (lane & 7) ^ (lane >> 3);
  const f16* aSrc = Am + (long long)(gm0 + srow) * K + sslot * 8;
  const f16* bSrc = Bm + (long long)(gn0 + srow) * K + sslot * 8;
  char* AsB = (char*)As;
  char* BsB = (char*)Bs;

  f32x4 zero = {0.f, 0.f, 0.f, 0.f};
  f32x4 acc[4][4];
  for (int i = 0; i < 4; ++i)
    for (int j = 0; j < 4; ++j) acc[i][j] = zero;

  for (int kt = 0; kt < K; kt += 64) {
    if (kt) __syncthreads();
#pragma unroll
    for (int q = 0; q < 4; ++q) {
      async16(aSrc + (long long)q * 8 * K + kt, AsB + (wave * 32 + q * 8) * 128);
      async16(bSrc + (long long)q * 8 * K + kt, BsB + (wave * 32 + q * 8) * 128);
    }
    __syncthreads();
#pragma unroll
    for (int ks = 0; ks < 2; ++ks) {
      f16x8 af[4], bf[4];
#pragma unroll
      for (int i = 0; i < 4; ++i) {
        int row = wr * 64 + i * 16 + (lane & 15);
        int slot = (ks * 4 + (lane >> 4)) ^ (row & 7);
        af[i] = *reinterpret_cast<const f16x8*>(AsB + row * 128 + slot * 16);
      }
#pragma unroll
      for (int j = 0; j < 4; ++j) {
        int row = wc * 64 + j * 16 + (lane & 15);
        int slot = (ks * 4 + (lane >> 4)) ^ (row & 7);
        bf[j] = *reinterpret_cast<const f16x8*>(BsB + row * 128 + slot * 16);
      }
#pragma unroll
      for (int i = 0; i < 4; ++i)
#pragma unroll
        for (int j = 0; j < 4; ++j)
          acc[i][j] = __builtin_amdgcn_mfma_f32_16x16x32_f16(af[i], bf[j], acc[i][j], 0, 0, 0);
    }
  }

  const int rowl = (lane >> 4) * 4;
  const int coll = lane & 15;
  for (int j = 0; j < 4; ++j) {
    int col = gn0 + wc * 64 + j * 16 + coll;
    float bv = bias[m * N + col];
    for (int i = 0; i < 4; ++i) {
      int row0 = gm0 + wr * 64 + i * 16 + rowl;
      for (int r = 0; r < 4; ++r) {
        float v = acc[i][j][r] + bv;
        v = v > 0.f ? v : 0.f;
        if constexpr (OUTF16) {
          outh[((long long)m * BBATCH + row0 + r) * N + col] = (f16)v;
        } else {
          outf[((long long)m * BBATCH + row0 + r) * N + col] = v;
          tH[((long long)(m * BBATCH + row0 + r) * 2 + (col & 1)) * 128 + (col >> 1)] = (f16)v;
        }
      }
    }
  }
}

// ---------------- pipelined GEMM: BM=256 BN=128 BK=64, 8 waves (4Mx2N), triple-buffered LDS,
// counted vmcnt(6) (never drain in main loop), setprio around MFMA, XCD-chunked block swizzle.
// Ledger: 6 global_load_lds per thread per K-tile. While computing tile t (buf t%3), tile t+1
// is resident (buf (t+1)%3), tile t+2 streams into buf (t+2)%3. vmcnt(6) at end of tile t
// => own t+1 loads landed, t+2's 6 in flight; barrier makes that true across all waves.
template <int OUTF16>
__global__ __launch_bounds__(512, 2) void k_gemm3(const f16* __restrict__ A,
                                                  const f16* __restrict__ BT,
                                                  const float* __restrict__ bias,
                                                  f16* __restrict__ outh,
                                                  float* __restrict__ outf,
                                                  f16* __restrict__ tH, int K, int N) {
  extern __shared__ char lds[];  // 3 * (A: 256*64*2 + B: 128*64*2) = 3 * 49152 = 147456 B
  // XCD-aware swizzle: nwg is always a multiple of 8 here (768/384/192).
  const int lin = blockIdx.x + gridDim.x * (blockIdx.y + gridDim.y * blockIdx.z);
  const int cpx = (gridDim.x * gridDim.y * gridDim.z) >> 3;
  const int swz = (lin & 7) * cpx + (lin >> 3);
  const int bx = swz % gridDim.x;
  const int rest = swz / gridDim.x;
  const int by = rest % gridDim.y;
  const int m = rest / gridDim.y;

  const int gm0 = by * 256;
  const int gn0 = bx * 128;
  const int tid = threadIdx.x;
  const int wave = tid >> 6, lane = tid & 63;
  const int wr = wave >> 2, wcq = wave & 3;  // placeholder (re-derived below)
  (void)wr; (void)wcq;
  const int wR = wave >> 1;  // 0..3: M quadrant (64 rows each)
  const int wC = wave & 1;   // 0..1: N half (64 cols each)

  const f16* Am = A + (long long)m * BBATCH * K;
  const f16* Bm = BT + (long long)m * N * K;

  // Staging addressing: pass covers 64 rows (8 KB). thread -> row = base + (tid>>3),
  // phys slot = tid&7; logical slot = phys ^ (row&7); row&7 == (tid>>3)&7 for all passes.
  const int srow = tid >> 3;
  const int slog = (tid & 7) ^ (srow & 7);
  const f16* aSrc = Am + (long long)(gm0 + srow) * K + slog * 8;
  const f16* bSrc = Bm + (long long)(gn0 + srow) * K + slog * 8;

  auto stageA = [&](int bq, int kt) {  // A passes 0..2 (rows 0..191)
    char* rg = lds + bq * 49152;
#pragma unroll
    for (int p = 0; p < 3; ++p)
      async16(aSrc + (long long)p * 64 * K + kt, rg + p * 8192 + wave * 1024);
  };
  auto stageB = [&](int bq, int kt) {  // A pass 3 (rows 192..255) + B passes 0,1
    char* rg = lds + bq * 49152;
    async16(aSrc + (long long)3 * 64 * K + kt, rg + 3 * 8192 + wave * 1024);
#pragma unroll
    for (int p = 0; p < 2; ++p)
      async16(bSrc + (long long)p * 64 * K + kt, rg + 32768 + p * 8192 + wave * 1024);
  };
  auto ldA = [&](const char* buf, int i, int ks) -> f16x8 {
    int row = wR * 64 + i * 16 + (lane & 15);
    int slot = (ks * 4 + (lane >> 4)) ^ (row & 7);
    return *reinterpret_cast<const f16x8*>(buf + row * 128 + slot * 16);
  };
  auto ldB = [&](const char* buf, int j, int ks) -> f16x8 {
    int row = wC * 64 + j * 16 + (lane & 15);
    int slot = (ks * 4 + (lane >> 4)) ^ (row & 7);
    return *reinterpret_cast<const f16x8*>(buf + 32768 + row * 128 + slot * 16);
  };

  f32x4 zero = {0.f, 0.f, 0.f, 0.f};
  f32x4 acc[4][4];
#pragma unroll
  for (int i = 0; i < 4; ++i)
#pragma unroll
    for (int j = 0; j < 4; ++j) acc[i][j] = zero;

  const int NT = K >> 6;
  // prologue: stage tiles 0 and 1; wait for tile 0 (6 outstanding = tile 1's).
  stageA(0, 0); stageB(0, 0);
  stageA(1, 64); stageB(1, 64);
  asm volatile("s_waitcnt vmcnt(6)" ::: "memory");
  __builtin_amdgcn_s_barrier();

  for (int t = 0; t < NT; ++t) {
    const char* buf = lds + (t % 3) * 49152;
    const int bq2 = (t + 2) % 3;
    const int kt2 = (t + 2) << 6;
    const bool st = (t + 2 < NT);
    f16x8 bf[2][4], af[2][2];
    // ---- phase A: frag-rows 0,1 ----
#pragma unroll
    for (int ks = 0; ks < 2; ++ks) {
#pragma unroll
      for (int j = 0; j < 4; ++j) bf[ks][j] = ldB(buf, j, ks);
#pragma unroll
      for (int i = 0; i < 2; ++i) af[ks][i] = ldA(buf, i, ks);
    }
    if (st) stageA(bq2, kt2);
    __builtin_amdgcn_s_barrier();
    __builtin_amdgcn_s_setprio(1);
#pragma unroll
    for (int ks = 0; ks < 2; ++ks)
#pragma unroll
      for (int i = 0; i < 2; ++i)
#pragma unroll
        for (int j = 0; j < 4; ++j)
          acc[i][j] = __builtin_amdgcn_mfma_f32_16x16x32_f16(af[ks][i], bf[ks][j], acc[i][j], 0, 0, 0);
    __builtin_amdgcn_s_setprio(0);
    __builtin_amdgcn_s_barrier();
    // ---- phase B: frag-rows 2,3 ----
#pragma unroll
    for (int ks = 0; ks < 2; ++ks)
#pragma unroll
      for (int i = 0; i < 2; ++i) af[ks][i] = ldA(buf, 2 + i, ks);
    if (st) stageB(bq2, kt2);
    __builtin_amdgcn_s_barrier();
    __builtin_amdgcn_s_setprio(1);
#pragma unroll
    for (int ks = 0; ks < 2; ++ks)
#pragma unroll
      for (int i = 0; i < 2; ++i)
#pragma unroll
        for (int j = 0; j < 4; ++j)
          acc[2 + i][j] = __builtin_amdgcn_mfma_f32_16x16x32_f16(af[ks][i], bf[ks][j], acc[2 + i][j], 0, 0, 0);
    __builtin_amdgcn_s_setprio(0);
    if (t < NT - 2) {
      asm volatile("s_waitcnt vmcnt(6)" ::: "memory");
    } else if (t == NT - 2) {
      asm volatile("s_waitcnt vmcnt(0)" ::: "memory");
    }
    __builtin_amdgcn_s_barrier();
  }

  const int rowl = (lane >> 4) * 4;
  const int coll = lane & 15;
  for (int j = 0; j < 4; ++j) {
    int col = gn0 + wC * 64 + j * 16 + coll;
    float bv = bias[m * N + col];
    for (int i = 0; i < 4; ++i) {
      int row0 = gm0 + wR * 64 + i * 16 + rowl;
      for (int r = 0; r < 4; ++r) {
        float v = acc[i][j][r] + bv;
        v = v > 0.f ? v : 0.f;
        if constexpr (OUTF16) {
          outh[((long long)m * BBATCH + row0 + r) * N + col] = (f16)v;
        } else {
          outf[((long long)m * BBATCH + row0 + r) * N + col] = v;
          tH[((long long)(m * BBATCH + row0 + r) * 2 + (col & 1)) * 128 + (col >> 1)] = (f16)v;
        }
      }
    }
  }
}

// ---------------- small GEMMs for the attention tail ----------------
__global__ __launch_bounds__(256, 2) void k_sg(const f16* __restrict__ tH,
                                               const f16* __restrict__ affH,
                                               const f16* __restrict__ WH,
                                               f16* __restrict__ u, float* __restrict__ WtG) {
  __shared__ f16 As[128 * 128];
  __shared__ f16 Bs[128 * 128];
  const int zb = blockIdx.z;
  const int gm0 = blockIdx.y * 128;
  const bool isU = (zb < 3);
  const int p = isU ? zb : zb - 3;
  const int src = isU ? ((p == 0) ? 1 : 2) : p;
  const f16* Am = tH + (long long)src * 16384 * 128;
  const f16* Bm;
  int brows;
  if (isU) {
    int km = (p == 1) ? 1 : 0;
    Bm = affH + km * 128 * 128;
    brows = 128;
  } else {
    Bm = WH + p * 64 * 128;
    brows = 64;
  }

  const int tid = threadIdx.x;
  const int wave = tid >> 6, lane = tid & 63;
  const int wr = wave >> 1, wc = wave & 1;
  char* AsB = (char*)As;
  char* BsB = (char*)Bs;

#pragma unroll
  for (int q = 0; q < 8; ++q) {
    int sb = q * 4 + wave;
    int row = sb * 4 + (lane >> 4);
    int lsl = (lane & 15) ^ (row & 7);
    async16(Am + (long long)(gm0 + row) * 128 + lsl * 8, AsB + sb * 1024);
    if (sb * 4 < brows)
      async16(Bm + (long long)row * 128 + lsl * 8, BsB + sb * 1024);
  }
  if (brows == 64) {
    f16x8 z8 = {};
    for (int idx = tid; idx < 1024; idx += 256) {
      int row = 64 + (idx >> 4), sl = idx & 15;
      *reinterpret_cast<f16x8*>(BsB + row * 256 + sl * 16) = z8;
    }
  }
  __syncthreads();

  f32x4 zero = {0.f, 0.f, 0.f, 0.f};
  f32x4 acc[4][4];
  for (int i = 0; i < 4; ++i)
    for (int j = 0; j < 4; ++j) acc[i][j] = zero;

#pragma unroll
  for (int ks = 0; ks < 4; ++ks) {
    f16x8 af[4], bf[4];
#pragma unroll
    for (int i = 0; i < 4; ++i) {
      int row = wr * 64 + i * 16 + (lane & 15);
      int slot = (ks * 4 + (lane >> 4)) ^ (row & 7);
      af[i] = *reinterpret_cast<const f16x8*>(AsB + row * 256 + slot * 16);
    }
#pragma unroll
    for (int j = 0; j < 4; ++j) {
      int row = wc * 64 + j * 16 + (lane & 15);
      int slot = (ks * 4 + (lane >> 4)) ^ (row & 7);
      bf[j] = *reinterpret_cast<const f16x8*>(BsB + row * 256 + slot * 16);
    }
#pragma unroll
    for (int i = 0; i < 4; ++i)
#pragma unroll
      for (int j = 0; j < 4; ++j)
        acc[i][j] = __builtin_amdgcn_mfma_f32_16x16x32_f16(af[i], bf[j], acc[i][j], 0, 0, 0);
  }

  const int rowl = (lane >> 4) * 4;
  const int coll = lane & 15;
  if (isU) {
    for (int j = 0; j < 4; ++j) {
      int col = wc * 64 + j * 16 + coll;
      for (int i = 0; i < 4; ++i) {
        int row0 = gm0 + wr * 64 + i * 16 + rowl;
        for (int r = 0; r < 4; ++r)
          u[((long long)p * 16384 + row0 + r) * 128 + col] = (f16)acc[i][j][r];
      }
    }
  } else if (wc == 0) {
    for (int j = 0; j < 4; ++j) {
      int col = j * 16 + coll;
      for (int i = 0; i < 4; ++i) {
        int row0 = gm0 + wr * 64 + i * 16 + rowl;
        for (int r = 0; r < 4; ++r)
          WtG[((long long)p * 16384 + row0 + r) * 64 + col] = acc[i][j][r];
      }
    }
  }
}

// ---------------- fused tail: afm dots + tanh/softmax + coalesced output ----------------
DEVI float dot128(const f16* __restrict__ a, const f16* __restrict__ b) {
  float s = 0.f;
#pragma unroll
  for (int ch = 0; ch < 16; ++ch) {
    f16x8 av = *reinterpret_cast<const f16x8*>(a + ch * 8);
    f16x8 bv = *reinterpret_cast<const f16x8*>(b + ch * 8);
#pragma unroll
    for (int q = 0; q < 8; ++q) s += (float)av[q] * (float)bv[q];
  }
  return s;
}

DEVI float ftanh(float x) {
  x = fminf(fmaxf(x, -15.f), 15.f);
  float t = __expf(-2.f * x);
  return (1.f - t) / (1.f + t);
}

#define BB 32
__global__ void k_tail(const float* __restrict__ z, const f16* __restrict__ tH,
                       const f16* __restrict__ u, const float* __restrict__ WtG,
                       const float* __restrict__ Wh, float* __restrict__ out) {
  __shared__ float aa[BB][6][2];
  const int tid = threadIdx.x;
  const int bbase = blockIdx.x * BB;

  if (tid < BB * 6) {
    int bb = tid / 6, q = tid % 6;
    int b = bbase + bb;
    int i = q >> 1;
    int j = (q & 1) ? ((i == 2) ? 1 : 2) : ((i == 0) ? 1 : 0);
    int a = i < j ? i : j;
    int b2 = i < j ? j : i;
    int pidx = a + b2 - 1;
    bool trans = (i > j);

    float afm[2][2];
#pragma unroll
    for (int c = 0; c < 2; ++c)
#pragma unroll
      for (int d = 0; d < 2; ++d)
        afm[c][d] = dot128(tH + ((long long)(a * BBATCH + b) * 2 + c) * 128,
                           u + ((long long)pidx * 16384 + b * 2 + d) * 128);

    float m00, m01, m10, m11;
    if (!trans) { m00 = afm[0][0]; m01 = afm[0][1]; m10 = afm[1][0]; m11 = afm[1][1]; }
    else        { m00 = afm[0][0]; m01 = afm[1][0]; m10 = afm[0][1]; m11 = afm[1][1]; }

    const float* wb0 = WtG + ((long long)b2 * 16384 + b * 2 + 0) * 64;
    const float* wb1 = WtG + ((long long)b2 * 16384 + b * 2 + 1) * 64;
    const float* wa0 = WtG + ((long long)a * 16384 + b * 2 + 0) * 64;
    const float* wa1 = WtG + ((long long)a * 16384 + b * 2 + 1) * 64;
    const float* wh = Wh + (i * 3 + j) * KATT;
    float s0 = 0.f, s1 = 0.f;
    for (int k = 0; k < KATT; ++k) {
      float a0v = wa0[k], a1v = wa1[k];
      float h0 = ftanh(wb0[k] + a0v * m00 + a1v * m10);
      float h1 = ftanh(wb1[k] + a0v * m01 + a1v * m11);
      float w = wh[k];
      s0 += w * h0;
      s1 += w * h1;
    }
    float mx = fmaxf(s0, s1);
    float e0 = __expf(s0 - mx), e1 = __expf(s1 - mx);
    float inv = 1.f / (e0 + e1);
    aa[bb][q][0] = e0 * inv;
    aa[bb][q][1] = e1 * inv;
  }
  __syncthreads();

  for (int idx = tid; idx < BB * 6 * 256; idx += 256) {
    int zz = idx & 255;
    int r = idx >> 8;
    int q = r % 6;
    int bb = r / 6;
    int iM = q >> 1;
    float av = aa[bb][q][zz & 1];
    float tv = z[((long long)iM * BBATCH + bbase + bb) * ZDIM + zz];
    out[(long long)(bbase + bb) * 1536 + q * 256 + zz] = av * tv;
  }
}

extern "C" void kernel_launch(void* const* d_in, const int* in_sizes, int n_in, void* d_out,
                              int out_size, void* d_ws, size_t ws_size, hipStream_t stream) {
  const float* x = (const float*)d_in[0];
  const float* w0 = (const float*)d_in[1];
  const float* b0 = (const float*)d_in[2];
  const float* w1 = (const float*)d_in[3];
  const float* b1 = (const float*)d_in[4];
  const float* w2 = (const float*)d_in[5];
  const float* b2 = (const float*)d_in[6];
  const float* aff = (const float*)d_in[7];
  const float* W = (const float*)d_in[8];
  const float* Wh = (const float*)d_in[9];
  float* zout = (float*)d_out;
  float* cout = zout + (long long)MM * BBATCH * ZDIM;

  char* ws = (char*)d_ws;
  size_t off = 0;
  auto alloc = [&](size_t bytes) {
    char* p = ws + off;
    off += (bytes + 255) & ~(size_t)255;
    return p;
  };
  f16* xh = (f16*)alloc((size_t)MM * BBATCH * K0P * 2);
  f16* wT0 = (f16*)alloc((size_t)MM * N0 * K0P * 2);
  f16* wT1 = (f16*)alloc((size_t)MM * N1 * N0 * 2);
  f16* wT2 = (f16*)alloc((size_t)MM * N2 * N1 * 2);
  f16* h0 = (f16*)alloc((size_t)MM * BBATCH * N0 * 2);
  f16* h1 = (f16*)alloc((size_t)MM * BBATCH * N1 * 2);
  f16* affH = (f16*)alloc((size_t)2 * 128 * 128 * 2);
  f16* WH = (f16*)alloc((size_t)3 * 64 * 128 * 2);
  if (ws_size < off) return;

  f16* tH = (f16*)xh;
  f16* u = (f16*)((char*)xh + (size_t)3 * 16384 * 128 * 2);
  float* WtG = (float*)((char*)xh + (size_t)2 * 3 * 16384 * 128 * 2);

  k_convx<<<4096, 256, 0, stream>>>(x, xh);
  k_convsmall<<<128, 256, 0, stream>>>(aff, W, affH, WH);
  k_wt<<<dim3(K0P / 32, N0 / 32, 3), 256, 0, stream>>>(w0, wT0, DDIM, K0P, N0);
  k_wt<<<dim3(N0 / 32, N1 / 32, 3), 256, 0, stream>>>(w1, wT1, N0, N0, N1);
  k_wt<<<dim3(N1 / 32, N2 / 32, 3), 256, 0, stream>>>(w2, wT2, N1, N1, N2);

  const int LDS3 = 3 * 49152;
  static_assert(3 * 49152 <= 160 * 1024, "LDS budget");
  hipError_t e1 = hipFuncSetAttribute(reinterpret_cast<const void*>(&k_gemm3<1>),
                                      hipFuncAttributeMaxDynamicSharedMemorySize, LDS3);
  hipError_t e2 = hipFuncSetAttribute(reinterpret_cast<const void*>(&k_gemm3<0>),
                                      hipFuncAttributeMaxDynamicSharedMemorySize, LDS3);
  if (e1 == hipSuccess && e2 == hipSuccess) {
    k_gemm3<1><<<dim3(N0 / 128, BBATCH / 256, 3), 512, LDS3, stream>>>(xh, wT0, b0, h0, nullptr, nullptr, K0P, N0);
    k_gemm3<1><<<dim3(N1 / 128, BBATCH / 256, 3), 512, LDS3, stream>>>(h0, wT1, b1, h1, nullptr, nullptr, N0, N1);
    k_gemm3<0><<<dim3(N2 / 128, BBATCH / 256, 3), 512, LDS3, stream>>>(h1, wT2, b2, nullptr, zout, tH, N1, N2);
  } else {
    k_gemm<1><<<dim3(N0 / 128, BBATCH / 128, 3), 256, 0, stream>>>(xh, wT0, b0, h0, nullptr, nullptr, K0P, N0);
    k_gemm<1><<<dim3(N1 / 128, BBATCH / 128, 3), 256, 0, stream>>>(h0, wT1, b1, h1, nullptr, nullptr, N0, N1);
    k_gemm<0><<<dim3(N2 / 128, BBATCH / 128, 3), 256, 0, stream>>>(h1, wT2, b2, nullptr, zout, tH, N1, N2);
  }
  k_sg<<<dim3(1, 128, 6), 256, 0, stream>>>(tH, affH, WH, u, WtG);
  k_tail<<<256, 256, 0, stream>>>(zout, tH, u, WtG, Wh, cout);
}

// Round 5
// 304.607 us; speedup vs baseline: 1.2352x; 1.0031x over previous
//
#include <hip/hip_runtime.h>

#define DEVI __device__ __forceinline__

typedef _Float16 f16;
typedef _Float16 f16x8 __attribute__((ext_vector_type(8)));
typedef float f32x4 __attribute__((ext_vector_type(4)));
typedef unsigned int u32;
typedef unsigned long long u64;

#define MM 3
#define BBATCH 8192
#define DDIM 2000
#define ZDIM 256
#define KATT 40
#define K0P 2048
#define N0 1024
#define N1 512
#define N2 256

typedef __attribute__((address_space(1))) u32 gu32;
typedef __attribute__((address_space(3))) u32 lu32;

DEVI void async16(const void* g, void* l) {
  __builtin_amdgcn_global_load_lds((const gu32*)g, (lu32*)l, 16, 0, 0);
}

// ---------------- x -> fp16, K padded 2000 -> 2048 ----------------
__global__ void k_convx(const float* __restrict__ x, f16* __restrict__ xh) {
  const long long nch = (long long)MM * BBATCH * (K0P / 8);
  for (long long idx = (long long)blockIdx.x * blockDim.x + threadIdx.x; idx < nch;
       idx += (long long)gridDim.x * blockDim.x) {
    int c8 = (int)(idx & 255);
    long long row = idx >> 8;
    union { f16 h[8]; f16x8 v; } u;
    if (c8 < DDIM / 8) {
      const float* src = x + row * DDIM + c8 * 8;
      float4 a = *reinterpret_cast<const float4*>(src);
      float4 b = *reinterpret_cast<const float4*>(src + 4);
      u.h[0] = (f16)a.x; u.h[1] = (f16)a.y; u.h[2] = (f16)a.z; u.h[3] = (f16)a.w;
      u.h[4] = (f16)b.x; u.h[5] = (f16)b.y; u.h[6] = (f16)b.z; u.h[7] = (f16)b.w;
    } else {
      for (int j = 0; j < 8; ++j) u.h[j] = (f16)0.f;
    }
    *reinterpret_cast<f16x8*>(xh + row * K0P + c8 * 8) = u.v;
  }
}

// ---------------- weight transpose+convert: w[m][K][N] f32 -> wt[m][N][Kpad] f16 ----------------
__global__ void k_wt(const float* __restrict__ w, f16* __restrict__ wt, int K, int Kpad, int N) {
  __shared__ float tile[32][33];
  int m = blockIdx.z;
  int k0 = blockIdx.x * 32, n0 = blockIdx.y * 32;
  const float* wm = w + (long long)m * K * N;
  f16* wtm = wt + (long long)m * N * Kpad;
  for (int p = 0; p < 4; ++p) {
    int idx = threadIdx.x + p * 256;
    int kk = idx >> 5, nn = idx & 31;
    float v = 0.f;
    if (k0 + kk < K) v = wm[(long long)(k0 + kk) * N + n0 + nn];
    tile[kk][nn] = v;
  }
  __syncthreads();
  for (int p = 0; p < 4; ++p) {
    int idx = threadIdx.x + p * 256;
    int nn = idx >> 5, kk = idx & 31;
    wtm[(long long)(n0 + nn) * Kpad + k0 + kk] = (f16)tile[kk][nn];
  }
}

// ---------------- small converts: aff -> f16, W -> f16 zero-padded [3][64][128] ----------------
__global__ void k_convsmall(const float* __restrict__ aff, const float* __restrict__ W,
                            f16* __restrict__ affH, f16* __restrict__ WH) {
  int idx = blockIdx.x * 256 + threadIdx.x;
  if (idx < 2 * 128 * 128) affH[idx] = (f16)aff[idx];
  if (idx < 3 * 64 * 128) {
    int m = idx >> 13;
    int k = (idx >> 7) & 63;
    int f = idx & 127;
    WH[idx] = (k < KATT) ? (f16)W[(m * KATT + k) * 128 + f] : (f16)0.f;
  }
}

// ---------------- legacy GEMM (fallback path), 128x128 tile, BK=64 ----------------
template <int OUTF16>
__global__ __launch_bounds__(256, 2) void k_gemm(const f16* __restrict__ A,
                                                 const f16* __restrict__ BT,
                                                 const float* __restrict__ bias,
                                                 f16* __restrict__ outh,
                                                 float* __restrict__ outf,
                                                 f16* __restrict__ tH, int K, int N) {
  __shared__ f16 As[128 * 64];
  __shared__ f16 Bs[128 * 64];
  const int m = blockIdx.z;
  const int gm0 = blockIdx.y * 128;
  const int gn0 = blockIdx.x * 128;
  const int tid = threadIdx.x;
  const int wave = tid >> 6, lane = tid & 63;
  const int wr = wave >> 1, wc = wave & 1;

  const f16* Am = A + (long long)m * BBATCH * K;
  const f16* Bm = BT + (long long)m * N * K;

  const int srow = wave * 32 + (lane >> 3);
  const int sslot = (lane & 7) ^ (lane >> 3);
  const f16* aSrc = Am + (long long)(gm0 + srow) * K + sslot * 8;
  const f16* bSrc = Bm + (long long)(gn0 + srow) * K + sslot * 8;
  char* AsB = (char*)As;
  char* BsB = (char*)Bs;

  f32x4 zero = {0.f, 0.f, 0.f, 0.f};
  f32x4 acc[4][4];
  for (int i = 0; i < 4; ++i)
    for (int j = 0; j < 4; ++j) acc[i][j] = zero;

  for (int kt = 0; kt < K; kt += 64) {
    if (kt) __syncthreads();
#pragma unroll
    for (int q = 0; q < 4; ++q) {
      async16(aSrc + (long long)q * 8 * K + kt, AsB + (wave * 32 + q * 8) * 128);
      async16(bSrc + (long long)q * 8 * K + kt, BsB + (wave * 32 + q * 8) * 128);
    }
    __syncthreads();
#pragma unroll
    for (int ks = 0; ks < 2; ++ks) {
      f16x8 af[4], bf[4];
#pragma unroll
      for (int i = 0; i < 4; ++i) {
        int row = wr * 64 + i * 16 + (lane & 15);
        int slot = (ks * 4 + (lane >> 4)) ^ (row & 7);
        af[i] = *reinterpret_cast<const f16x8*>(AsB + row * 128 + slot * 16);
      }
#pragma unroll
      for (int j = 0; j < 4; ++j) {
        int row = wc * 64 + j * 16 + (lane & 15);
        int slot = (ks * 4 + (lane >> 4)) ^ (row & 7);
        bf[j] = *reinterpret_cast<const f16x8*>(BsB + row * 128 + slot * 16);
      }
#pragma unroll
      for (int i = 0; i < 4; ++i)
#pragma unroll
        for (int j = 0; j < 4; ++j)
          acc[i][j] = __builtin_amdgcn_mfma_f32_16x16x32_f16(af[i], bf[j], acc[i][j], 0, 0, 0);
    }
  }

  const int rowl = (lane >> 4) * 4;
  const int coll = lane & 15;
  for (int j = 0; j < 4; ++j) {
    int col = gn0 + wc * 64 + j * 16 + coll;
    float bv = bias[m * N + col];
    for (int i = 0; i < 4; ++i) {
      int row0 = gm0 + wr * 64 + i * 16 + rowl;
      for (int r = 0; r < 4; ++r) {
        float v = acc[i][j][r] + bv;
        v = v > 0.f ? v : 0.f;
        if constexpr (OUTF16) {
          outh[((long long)m * BBATCH + row0 + r) * N + col] = (f16)v;
        } else {
          outf[((long long)m * BBATCH + row0 + r) * N + col] = v;
          tH[((long long)(m * BBATCH + row0 + r) * 2 + (col & 1)) * 128 + (col >> 1)] = (f16)v;
        }
      }
    }
  }
}

// ---------------- 8-phase 256x256 GEMM, reads-after-guarantee (race-fixed) ----------------
// 512 thr = 8 waves (2M x 4N), per-wave C = 128x64 over 4 quadrants; LDS 128 KB dbuf.
// Phase = { stage(t+1,h); vmcnt(6); s_barrier; ds_read frags; lgkmcnt(0); sched_barrier;
//           setprio(1) 16xMFMA setprio(0); s_barrier }   — P3 is reg-only (no sync needed).
// Ledger (stage S(n) at global phase n=4t+p, 2 loads each; vmcnt(6) => stages <= n-3 retired
// BEFORE this phase's ds_reads): P0 reads A0(t) staged n-4, B0(t) staged n-3 OK;
// P1 reads B1(t) staged n-3 OK; P2 reads A1(t) staged n-3 OK. Steady outstanding = 6.
// Epilogue tile: vmcnt 4/2/0. WAR on buf reuse guarded by P2's end-barrier (all reads of
// buf[t&1] retire via lgkmcnt(0) before it; stage(t+2,0) issues only after).

#define LDA_FRAGS(QM)                                                            \
  _Pragma("unroll") for (int ks = 0; ks < 2; ++ks)                               \
  _Pragma("unroll") for (int mf = 0; mf < 4; ++mf) {                             \
    const int row_ = (QM)*128 + wrB + mf * 16 + lrow;                            \
    af[ks][mf] = *reinterpret_cast<const f16x8*>(bufA + row_ * 128 + sl16[ks]);  \
  }

#define LDB_FRAGS(QN)                                                            \
  _Pragma("unroll") for (int ks = 0; ks < 2; ++ks)                               \
  _Pragma("unroll") for (int nf = 0; nf < 2; ++nf) {                             \
    const int row_ = (QN)*128 + wcB + nf * 16 + lrow;                            \
    bf[ks][QN][nf] = *reinterpret_cast<const f16x8*>(bufB + row_ * 128 + sl16[ks]); \
  }

#define DO_MFMA(QI, QN)                                                          \
  __builtin_amdgcn_s_setprio(1);                                                 \
  _Pragma("unroll") for (int ks = 0; ks < 2; ++ks)                               \
  _Pragma("unroll") for (int mf = 0; mf < 4; ++mf)                               \
  _Pragma("unroll") for (int nf = 0; nf < 2; ++nf)                               \
    acc[QI][mf * 2 + nf] = __builtin_amdgcn_mfma_f32_16x16x32_f16(                \
        af[ks][mf], bf[ks][QN][nf], acc[QI][mf * 2 + nf], 0, 0, 0);              \
  __builtin_amdgcn_s_setprio(0);

#define SYNCV(VMN)                                         \
  asm volatile("s_waitcnt vmcnt(" #VMN ")" ::: "memory");  \
  __builtin_amdgcn_s_barrier();

#define LGKM0                                              \
  asm volatile("s_waitcnt lgkmcnt(0)" ::: "memory");       \
  __builtin_amdgcn_sched_barrier(0);

#define ENDBAR __builtin_amdgcn_s_barrier();

template <int OUTF16>
__global__ __launch_bounds__(512, 2) void k_gemm8(const f16* __restrict__ A,
                                                  const f16* __restrict__ BT,
                                                  const float* __restrict__ bias,
                                                  f16* __restrict__ outh,
                                                  float* __restrict__ outf,
                                                  f16* __restrict__ tH, int K, int N) {
  extern __shared__ char lds[];  // 2 * 65536
  // XCD-aware bijective swizzle (nwg always a multiple of 8: 384/192/96).
  const int lin = blockIdx.y * gridDim.x + blockIdx.x;
  const int cpx = (gridDim.x * gridDim.y) >> 3;
  const int swz = (lin & 7) * cpx + (lin >> 3);
  const int bx = swz % gridDim.x;
  const int byy = swz / gridDim.x;  // 0..95
  const int m = byy >> 5;
  const int gm0 = (byy & 31) * 256;
  const int gn0 = bx * 256;

  const int tid = threadIdx.x;
  const int wave = tid >> 6, lane = tid & 63;
  const int wrB = (wave >> 2) * 64;  // M offset within 128-row quadrant half
  const int wcB = (wave & 3) * 32;   // N offset within 128-col quadrant half
  const int lrow = lane & 15;
  int sl16[2];
#pragma unroll
  for (int ks = 0; ks < 2; ++ks) sl16[ks] = (((ks * 4) + (lane >> 4)) ^ (lane & 7)) * 16;

  const f16* Am = A + (long long)m * BBATCH * K;
  const f16* Bm = BT + (long long)m * N * K;
  const int srow = tid >> 3;                // 0..63
  const int slog = (tid & 7) ^ (srow & 7);  // pre-swizzled logical slot for phys slot tid&7

  // hsel: 0=A half0, 1=B half0, 2=B half1, 3=A half1
  auto stage = [&](int t, int hsel) {
    const int isB = (hsel == 1 || hsel == 2) ? 1 : 0;
    const int h = (hsel == 2 || hsel == 3) ? 1 : 0;
    const long long grow = (long long)(isB ? gn0 : gm0) + h * 128 + srow;
    const f16* src = (isB ? Bm : Am) + grow * K + ((long long)t << 6) + slog * 8;
    char* dst = lds + ((t & 1) << 16) + isB * 32768 + h * 16384 + srow * 128 + (tid & 7) * 16;
    async16(src, dst);
    async16(src + (long long)64 * K, dst + 8192);
  };

  f16x8 af[2][4];
  f16x8 bf[2][2][2];  // [ks][qn][nf]
  f32x4 acc[4][8];    // [quadrant][mf*2+nf]
  f32x4 zero = {0.f, 0.f, 0.f, 0.f};
#pragma unroll
  for (int qi = 0; qi < 4; ++qi)
#pragma unroll
    for (int f = 0; f < 8; ++f) acc[qi][f] = zero;

  const int NT = K >> 6;
  stage(0, 0); stage(0, 1); stage(0, 2); stage(0, 3);

  for (int t = 0; t < NT - 1; ++t) {
    const char* bufA = lds + ((t & 1) << 16);
    const char* bufB = bufA + 32768;
    stage(t + 1, 0);
    SYNCV(6)
    LDA_FRAGS(0) LDB_FRAGS(0) LGKM0
    DO_MFMA(0, 0) ENDBAR
    stage(t + 1, 1);
    SYNCV(6)
    LDB_FRAGS(1) LGKM0
    DO_MFMA(1, 1) ENDBAR
    stage(t + 1, 2);
    SYNCV(6)
    LDA_FRAGS(1) LGKM0
    DO_MFMA(2, 1) ENDBAR
    stage(t + 1, 3);
    DO_MFMA(3, 0)
  }
  {
    const int t = NT - 1;
    const char* bufA = lds + ((t & 1) << 16);
    const char* bufB = bufA + 32768;
    SYNCV(4)
    LDA_FRAGS(0) LDB_FRAGS(0) LGKM0
    DO_MFMA(0, 0) ENDBAR
    SYNCV(2)
    LDB_FRAGS(1) LGKM0
    DO_MFMA(1, 1) ENDBAR
    SYNCV(0)
    LDA_FRAGS(1) LGKM0
    DO_MFMA(2, 1) ENDBAR
    DO_MFMA(3, 0)
  }

  const int rowl = (lane >> 4) * 4;
  const int coll = lane & 15;
#pragma unroll
  for (int qi = 0; qi < 4; ++qi) {
    const int qm = (qi >= 2) ? 1 : 0;
    const int qn = (qi == 1 || qi == 2) ? 1 : 0;
#pragma unroll
    for (int nf = 0; nf < 2; ++nf) {
      int col = gn0 + qn * 128 + wcB + nf * 16 + coll;
      float bv = bias[m * N + col];
#pragma unroll
      for (int mf = 0; mf < 4; ++mf) {
        int row0 = gm0 + qm * 128 + wrB + mf * 16 + rowl;
#pragma unroll
        for (int r = 0; r < 4; ++r) {
          float v = acc[qi][mf * 2 + nf][r] + bv;
          v = v > 0.f ? v : 0.f;
          if constexpr (OUTF16) {
            outh[((long long)m * BBATCH + row0 + r) * N + col] = (f16)v;
          } else {
            outf[((long long)m * BBATCH + row0 + r) * N + col] = v;
            tH[((long long)(m * BBATCH + row0 + r) * 2 + (col & 1)) * 128 + (col >> 1)] = (f16)v;
          }
        }
      }
    }
  }
}

// ---------------- small GEMMs for the attention tail ----------------
__global__ __launch_bounds__(256, 2) void k_sg(const f16* __restrict__ tH,
                                               const f16* __restrict__ affH,
                                               const f16* __restrict__ WH,
                                               f16* __restrict__ u, float* __restrict__ WtG) {
  __shared__ f16 As[128 * 128];
  __shared__ f16 Bs[128 * 128];
  const int zb = blockIdx.z;
  const int gm0 = blockIdx.y * 128;
  const bool isU = (zb < 3);
  const int p = isU ? zb : zb - 3;
  const int src = isU ? ((p == 0) ? 1 : 2) : p;
  const f16* Am = tH + (long long)src * 16384 * 128;
  const f16* Bm;
  int brows;
  if (isU) {
    int km = (p == 1) ? 1 : 0;
    Bm = affH + km * 128 * 128;
    brows = 128;
  } else {
    Bm = WH + p * 64 * 128;
    brows = 64;
  }

  const int tid = threadIdx.x;
  const int wave = tid >> 6, lane = tid & 63;
  const int wr = wave >> 1, wc = wave & 1;
  char* AsB = (char*)As;
  char* BsB = (char*)Bs;

#pragma unroll
  for (int q = 0; q < 8; ++q) {
    int sb = q * 4 + wave;
    int row = sb * 4 + (lane >> 4);
    int lsl = (lane & 15) ^ (row & 7);
    async16(Am + (long long)(gm0 + row) * 128 + lsl * 8, AsB + sb * 1024);
    if (sb * 4 < brows)
      async16(Bm + (long long)row * 128 + lsl * 8, BsB + sb * 1024);
  }
  if (brows == 64) {
    f16x8 z8 = {};
    for (int idx = tid; idx < 1024; idx += 256) {
      int row = 64 + (idx >> 4), sl = idx & 15;
      *reinterpret_cast<f16x8*>(BsB + row * 256 + sl * 16) = z8;
    }
  }
  __syncthreads();

  f32x4 zero = {0.f, 0.f, 0.f, 0.f};
  f32x4 acc[4][4];
  for (int i = 0; i < 4; ++i)
    for (int j = 0; j < 4; ++j) acc[i][j] = zero;

#pragma unroll
  for (int ks = 0; ks < 4; ++ks) {
    f16x8 af[4], bf[4];
#pragma unroll
    for (int i = 0; i < 4; ++i) {
      int row = wr * 64 + i * 16 + (lane & 15);
      int slot = (ks * 4 + (lane >> 4)) ^ (row & 7);
      af[i] = *reinterpret_cast<const f16x8*>(AsB + row * 256 + slot * 16);
    }
#pragma unroll
    for (int j = 0; j < 4; ++j) {
      int row = wc * 64 + j * 16 + (lane & 15);
      int slot = (ks * 4 + (lane >> 4)) ^ (row & 7);
      bf[j] = *reinterpret_cast<const f16x8*>(BsB + row * 256 + slot * 16);
    }
#pragma unroll
    for (int i = 0; i < 4; ++i)
#pragma unroll
      for (int j = 0; j < 4; ++j)
        acc[i][j] = __builtin_amdgcn_mfma_f32_16x16x32_f16(af[i], bf[j], acc[i][j], 0, 0, 0);
  }

  const int rowl = (lane >> 4) * 4;
  const int coll = lane & 15;
  if (isU) {
    for (int j = 0; j < 4; ++j) {
      int col = wc * 64 + j * 16 + coll;
      for (int i = 0; i < 4; ++i) {
        int row0 = gm0 + wr * 64 + i * 16 + rowl;
        for (int r = 0; r < 4; ++r)
          u[((long long)p * 16384 + row0 + r) * 128 + col] = (f16)acc[i][j][r];
      }
    }
  } else if (wc == 0) {
    for (int j = 0; j < 4; ++j) {
      int col = j * 16 + coll;
      for (int i = 0; i < 4; ++i) {
        int row0 = gm0 + wr * 64 + i * 16 + rowl;
        for (int r = 0; r < 4; ++r)
          WtG[((long long)p * 16384 + row0 + r) * 64 + col] = acc[i][j][r];
      }
    }
  }
}

// ---------------- fused tail: afm dots + tanh/softmax + coalesced output ----------------
DEVI float dot128(const f16* __restrict__ a, const f16* __restrict__ b) {
  float s = 0.f;
#pragma unroll
  for (int ch = 0; ch < 16; ++ch) {
    f16x8 av = *reinterpret_cast<const f16x8*>(a + ch * 8);
    f16x8 bv = *reinterpret_cast<const f16x8*>(b + ch * 8);
#pragma unroll
    for (int q = 0; q < 8; ++q) s += (float)av[q] * (float)bv[q];
  }
  return s;
}

DEVI float ftanh(float x) {
  x = fminf(fmaxf(x, -15.f), 15.f);
  float t = __expf(-2.f * x);
  return (1.f - t) / (1.f + t);
}

#define BB 32
__global__ void k_tail(const float* __restrict__ z, const f16* __restrict__ tH,
                       const f16* __restrict__ u, const float* __restrict__ WtG,
                       const float* __restrict__ Wh, float* __restrict__ out) {
  __shared__ float aa[BB][6][2];
  const int tid = threadIdx.x;
  const int bbase = blockIdx.x * BB;

  if (tid < BB * 6) {
    int bb = tid / 6, q = tid % 6;
    int b = bbase + bb;
    int i = q >> 1;
    int j = (q & 1) ? ((i == 2) ? 1 : 2) : ((i == 0) ? 1 : 0);
    int a = i < j ? i : j;
    int b2 = i < j ? j : i;
    int pidx = a + b2 - 1;
    bool trans = (i > j);

    float afm[2][2];
#pragma unroll
    for (int c = 0; c < 2; ++c)
#pragma unroll
      for (int d = 0; d < 2; ++d)
        afm[c][d] = dot128(tH + ((long long)(a * BBATCH + b) * 2 + c) * 128,
                           u + ((long long)pidx * 16384 + b * 2 + d) * 128);

    float m00, m01, m10, m11;
    if (!trans) { m00 = afm[0][0]; m01 = afm[0][1]; m10 = afm[1][0]; m11 = afm[1][1]; }
    else        { m00 = afm[0][0]; m01 = afm[1][0]; m10 = afm[0][1]; m11 = afm[1][1]; }

    const float* wb0 = WtG + ((long long)b2 * 16384 + b * 2 + 0) * 64;
    const float* wb1 = WtG + ((long long)b2 * 16384 + b * 2 + 1) * 64;
    const float* wa0 = WtG + ((long long)a * 16384 + b * 2 + 0) * 64;
    const float* wa1 = WtG + ((long long)a * 16384 + b * 2 + 1) * 64;
    const float* wh = Wh + (i * 3 + j) * KATT;
    float s0 = 0.f, s1 = 0.f;
    for (int k = 0; k < KATT; ++k) {
      float a0v = wa0[k], a1v = wa1[k];
      float h0 = ftanh(wb0[k] + a0v * m00 + a1v * m10);
      float h1 = ftanh(wb1[k] + a0v * m01 + a1v * m11);
      float w = wh[k];
      s0 += w * h0;
      s1 += w * h1;
    }
    float mx = fmaxf(s0, s1);
    float e0 = __expf(s0 - mx), e1 = __expf(s1 - mx);
    float inv = 1.f / (e0 + e1);
    aa[bb][q][0] = e0 * inv;
    aa[bb][q][1] = e1 * inv;
  }
  __syncthreads();

  for (int idx = tid; idx < BB * 6 * 256; idx += 256) {
    int zz = idx & 255;
    int r = idx >> 8;
    int q = r % 6;
    int bb = r / 6;
    int iM = q >> 1;
    float av = aa[bb][q][zz & 1];
    float tv = z[((long long)iM * BBATCH + bbase + bb) * ZDIM + zz];
    out[(long long)(bbase + bb) * 1536 + q * 256 + zz] = av * tv;
  }
}

extern "C" void kernel_launch(void* const* d_in, const int* in_sizes, int n_in, void* d_out,
                              int out_size, void* d_ws, size_t ws_size, hipStream_t stream) {
  const float* x = (const float*)d_in[0];
  const float* w0 = (const float*)d_in[1];
  const float* b0 = (const float*)d_in[2];
  const float* w1 = (const float*)d_in[3];
  const float* b1 = (const float*)d_in[4];
  const float* w2 = (const float*)d_in[5];
  const float* b2 = (const float*)d_in[6];
  const float* aff = (const float*)d_in[7];
  const float* W = (const float*)d_in[8];
  const float* Wh = (const float*)d_in[9];
  float* zout = (float*)d_out;
  float* cout = zout + (long long)MM * BBATCH * ZDIM;

  char* ws = (char*)d_ws;
  size_t off = 0;
  auto alloc = [&](size_t bytes) {
    char* p = ws + off;
    off += (bytes + 255) & ~(size_t)255;
    return p;
  };
  f16* xh = (f16*)alloc((size_t)MM * BBATCH * K0P * 2);
  f16* wT0 = (f16*)alloc((size_t)MM * N0 * K0P * 2);
  f16* wT1 = (f16*)alloc((size_t)MM * N1 * N0 * 2);
  f16* wT2 = (f16*)alloc((size_t)MM * N2 * N1 * 2);
  f16* h0 = (f16*)alloc((size_t)MM * BBATCH * N0 * 2);
  f16* h1 = (f16*)alloc((size_t)MM * BBATCH * N1 * 2);
  f16* affH = (f16*)alloc((size_t)2 * 128 * 128 * 2);
  f16* WH = (f16*)alloc((size_t)3 * 64 * 128 * 2);
  if (ws_size < off) return;

  f16* tH = (f16*)xh;
  f16* u = (f16*)((char*)xh + (size_t)3 * 16384 * 128 * 2);
  float* WtG = (float*)((char*)xh + (size_t)2 * 3 * 16384 * 128 * 2);

  k_convx<<<4096, 256, 0, stream>>>(x, xh);
  k_convsmall<<<128, 256, 0, stream>>>(aff, W, affH, WH);
  k_wt<<<dim3(K0P / 32, N0 / 32, 3), 256, 0, stream>>>(w0, wT0, DDIM, K0P, N0);
  k_wt<<<dim3(N0 / 32, N1 / 32, 3), 256, 0, stream>>>(w1, wT1, N0, N0, N1);
  k_wt<<<dim3(N1 / 32, N2 / 32, 3), 256, 0, stream>>>(w2, wT2, N1, N1, N2);

  const int LDS8 = 2 * 65536;
  hipError_t e1 = hipFuncSetAttribute(reinterpret_cast<const void*>(&k_gemm8<1>),
                                      hipFuncAttributeMaxDynamicSharedMemorySize, LDS8);
  hipError_t e2 = hipFuncSetAttribute(reinterpret_cast<const void*>(&k_gemm8<0>),
                                      hipFuncAttributeMaxDynamicSharedMemorySize, LDS8);
  if (e1 == hipSuccess && e2 == hipSuccess) {
    k_gemm8<1><<<dim3(N0 / 256, 96), 512, LDS8, stream>>>(xh, wT0, b0, h0, nullptr, nullptr, K0P, N0);
    k_gemm8<1><<<dim3(N1 / 256, 96), 512, LDS8, stream>>>(h0, wT1, b1, h1, nullptr, nullptr, N0, N1);
    k_gemm8<0><<<dim3(N2 / 256, 96), 512, LDS8, stream>>>(h1, wT2, b2, nullptr, zout, tH, N1, N2);
  } else {
    k_gemm<1><<<dim3(N0 / 128, BBATCH / 128, 3), 256, 0, stream>>>(xh, wT0, b0, h0, nullptr, nullptr, K0P, N0);
    k_gemm<1><<<dim3(N1 / 128, BBATCH / 128, 3), 256, 0, stream>>>(h0, wT1, b1, h1, nullptr, nullptr, N0, N1);
    k_gemm<0><<<dim3(N2 / 128, BBATCH / 128, 3), 256, 0, stream>>>(h1, wT2, b2, nullptr, zout, tH, N1, N2);
  }
  k_sg<<<dim3(1, 128, 6), 256, 0, stream>>>(tH, affH, WH, u, WtG);
  k_tail<<<256, 256, 0, stream>>>(zout, tH, u, WtG, Wh, cout);
}